// Round 1
// baseline (870.369 us; speedup 1.0000x reference)
//
#include <hip/hip_runtime.h>

// Node_Embedding: HeteroGraphConv(sum) of 4 GraphConv relations + PReLU.
// Restructure: out_dsttype = (segsum(x_norm[src])·degin^-1/2) @ W + b, using
// matmul-linearity, so the scatter runs on raw x rows and the GEMM is fused
// after aggregation. CSR-by-dst via counting sort avoids float atomics.

#define NB 50000   // nodes per type
#define EB 500000  // edges per relation
#define D  128

struct EdgePtrs { const int* src[4]; const int* dst[4]; };

__global__ void k_degrees(EdgePtrs ep, int* __restrict__ degout, int* __restrict__ degin) {
    int e = blockIdx.x * blockDim.x + threadIdx.x;
    int r = blockIdx.y;
    if (e < EB) {
        atomicAdd(&degout[r * NB + ep.src[r][e]], 1);
        atomicAdd(&degin[r * NB + ep.dst[r][e]], 1);
    }
}

// Convert degree counts -> deg^{-1/2} (clip min 1). degout converted in place
// (int slot reused as float); degin kept intact (scan needs it), dinvin separate.
__global__ void k_dinv(int* __restrict__ degout, const int* __restrict__ degin,
                       float* __restrict__ dinvin) {
    int i = blockIdx.x * blockDim.x + threadIdx.x;
    if (i < 4 * NB) {
        int c = degout[i];
        ((float*)degout)[i] = rsqrtf((float)(c > 1 ? c : 1));
        int c2 = degin[i];
        dinvin[i] = rsqrtf((float)(c2 > 1 ? c2 : 1));
    }
}

// Exclusive scan of degin counts -> CSR offsets. One block per relation.
__global__ __launch_bounds__(1024) void k_scan(const int* __restrict__ degin,
                                               int* __restrict__ offs) {
    int r = blockIdx.x;
    const int* cnt = degin + r * NB;
    int* o = offs + r * (NB + 1);
    __shared__ int part[1024];
    int t = threadIdx.x;
    const int CH = (NB + 1023) / 1024;  // 49
    int lo = t * CH, hi = lo + CH; if (hi > NB) hi = NB;
    int s = 0;
    for (int i = lo; i < hi && i < NB; ++i) s += cnt[i];
    part[t] = s;
    __syncthreads();
    for (int off = 1; off < 1024; off <<= 1) {
        int v = (t >= off) ? part[t - off] : 0;
        __syncthreads();
        part[t] += v;
        __syncthreads();
    }
    int run = (t == 0) ? 0 : part[t - 1];
    for (int i = lo; i < hi && i < NB; ++i) { o[i] = run; run += cnt[i]; }
    if (t == 1023) o[NB] = part[1023];
}

__global__ void k_fill(EdgePtrs ep, const int* __restrict__ offs,
                       int* __restrict__ cursor, int* __restrict__ ssrc) {
    int e = blockIdx.x * blockDim.x + threadIdx.x;
    int r = blockIdx.y;
    if (e < EB) {
        int s = ep.src[r][e], d = ep.dst[r][e];
        int pos = atomicAdd(&cursor[r * NB + d], 1);
        ssrc[r * EB + offs[r * (NB + 1) + d] + pos] = s;
    }
}

// Fused gather + GEMM + bias + PReLU for one dst node type (two relations).
// Block: 256 threads, 32 dst rows. Stage 1: gather S[32][256] into LDS
// (cols 0-127 from relation A, 128-255 from relation B), already fully
// normalized. Stage 2: [32,256]@[256,128] register-tile GEMM, 4x4 per thread.
__global__ __launch_bounds__(256) void k_fused(
    const float* __restrict__ xA, const float* __restrict__ dvoA,
    const int* __restrict__ offsA, const int* __restrict__ ssA,
    const float* __restrict__ dviA, const float* __restrict__ WA,
    const float* __restrict__ xB, const float* __restrict__ dvoB,
    const int* __restrict__ offsB, const int* __restrict__ ssB,
    const float* __restrict__ dviB, const float* __restrict__ WB,
    const float* __restrict__ bA, const float* __restrict__ bB,
    const float* __restrict__ prelu_a, float* __restrict__ out) {
    __shared__ float slds[32][256];
    const int tid = threadIdx.x;
    const int row0 = blockIdx.x * 32;
    const int wave = tid >> 6, lane = tid & 63;
    const int c0 = lane * 2;

    // ---- stage 1: gather ----
    for (int i = 0; i < 16; ++i) {
        int seg = wave + 4 * i;           // 64 segments: (row_local, rel)
        int rl = seg >> 1, rel = seg & 1; // wave-uniform
        int d = row0 + rl;
        if (d < NB) {
            const float* x   = rel ? xB   : xA;
            const float* dvo = rel ? dvoB : dvoA;
            const int*  offs = rel ? offsB : offsA;
            const int*  ss   = rel ? ssB  : ssA;
            const float* dvi = rel ? dviB : dviA;
            float ax = 0.f, ay = 0.f;
            int beg = offs[d], end = offs[d + 1];
            for (int e = beg; e < end; ++e) {
                int s = ss[e];
                float sc = dvo[s];
                float2 xv = *reinterpret_cast<const float2*>(x + (size_t)s * D + c0);
                ax = fmaf(xv.x, sc, ax);
                ay = fmaf(xv.y, sc, ay);
            }
            float di = dvi[d];
            slds[rl][rel * 128 + c0]     = ax * di;
            slds[rl][rel * 128 + c0 + 1] = ay * di;
        }
    }
    __syncthreads();

    // ---- stage 2: GEMM ----
    const int jc = tid & 31, rg = tid >> 5;
    const int j0 = jc * 4, r0 = rg * 4;
    float acc[4][4];
#pragma unroll
    for (int i = 0; i < 4; ++i)
#pragma unroll
        for (int m = 0; m < 4; ++m) acc[i][m] = 0.f;

#pragma unroll 4
    for (int k = 0; k < 128; ++k) {
        float4 w = *reinterpret_cast<const float4*>(WA + k * D + j0);
#pragma unroll
        for (int i = 0; i < 4; ++i) {
            float sv = slds[r0 + i][k];
            acc[i][0] = fmaf(sv, w.x, acc[i][0]);
            acc[i][1] = fmaf(sv, w.y, acc[i][1]);
            acc[i][2] = fmaf(sv, w.z, acc[i][2]);
            acc[i][3] = fmaf(sv, w.w, acc[i][3]);
        }
    }
#pragma unroll 4
    for (int k = 0; k < 128; ++k) {
        float4 w = *reinterpret_cast<const float4*>(WB + k * D + j0);
#pragma unroll
        for (int i = 0; i < 4; ++i) {
            float sv = slds[r0 + i][128 + k];
            acc[i][0] = fmaf(sv, w.x, acc[i][0]);
            acc[i][1] = fmaf(sv, w.y, acc[i][1]);
            acc[i][2] = fmaf(sv, w.z, acc[i][2]);
            acc[i][3] = fmaf(sv, w.w, acc[i][3]);
        }
    }

    // ---- epilogue: bias + PReLU + store ----
    float a = prelu_a[0];
    float4 bb;
    bb.x = bA[j0 + 0] + bB[j0 + 0];
    bb.y = bA[j0 + 1] + bB[j0 + 1];
    bb.z = bA[j0 + 2] + bB[j0 + 2];
    bb.w = bA[j0 + 3] + bB[j0 + 3];
#pragma unroll
    for (int i = 0; i < 4; ++i) {
        int d = row0 + r0 + i;
        if (d < NB) {
            float4 v;
            v.x = acc[i][0] + bb.x;
            v.y = acc[i][1] + bb.y;
            v.z = acc[i][2] + bb.z;
            v.w = acc[i][3] + bb.w;
            v.x = v.x >= 0.f ? v.x : a * v.x;
            v.y = v.y >= 0.f ? v.y : a * v.y;
            v.z = v.z >= 0.f ? v.z : a * v.z;
            v.w = v.w >= 0.f ? v.w : a * v.w;
            *reinterpret_cast<float4*>(out + (size_t)d * D + j0) = v;
        }
    }
}

extern "C" void kernel_launch(void* const* d_in, const int* in_sizes, int n_in,
                              void* d_out, int out_size, void* d_ws, size_t ws_size,
                              hipStream_t stream) {
    const float* x_drug = (const float*)d_in[0];
    const float* x_dis  = (const float*)d_in[1];
    const float* W      = (const float*)d_in[2];   // [4,128,128]
    const float* b      = (const float*)d_in[3];   // [4,128]
    const float* pa     = (const float*)d_in[4];   // [1]
    EdgePtrs ep;
    ep.src[0] = (const int*)d_in[5];  ep.dst[0] = (const int*)d_in[6];   // dd
    ep.src[1] = (const int*)d_in[7];  ep.dst[1] = (const int*)d_in[8];   // ds
    ep.src[2] = (const int*)d_in[9];  ep.dst[2] = (const int*)d_in[10];  // sd
    ep.src[3] = (const int*)d_in[11]; ep.dst[3] = (const int*)d_in[12];  // ss

    // workspace layout (bytes)
    char* ws = (char*)d_ws;
    int*   degout = (int*)(ws + 0);         // 4*NB ints -> reused as float dinvout
    int*   degin  = (int*)(ws + 800000);    // 4*NB ints
    int*   cursor = (int*)(ws + 1600000);   // 4*NB ints
    float* dinvin = (float*)(ws + 2400000); // 4*NB floats
    int*   offs   = (int*)(ws + 3200000);   // 4*(NB+1) ints
    int*   ssrc   = (int*)(ws + 4000016);   // 4*EB ints  (total ~12 MB)

    hipMemsetAsync(ws, 0, 2400000, stream);  // degout, degin, cursor

    dim3 gE((EB + 255) / 256, 4);
    k_degrees<<<gE, 256, 0, stream>>>(ep, degout, degin);
    k_dinv<<<(4 * NB + 255) / 256, 256, 0, stream>>>(degout, degin, dinvin);
    k_scan<<<4, 1024, 0, stream>>>(degin, offs);
    k_fill<<<gE, 256, 0, stream>>>(ep, offs, cursor, ssrc);

    const float* dinvout = (const float*)degout;
    int nblk = (NB + 31) / 32;  // 1563

    // dst = drug: relation dd (A: x_drug,W0,b0) + relation sd (B: x_dis,W2,b2)
    k_fused<<<nblk, 256, 0, stream>>>(
        x_drug, dinvout + 0 * NB, offs + 0 * (NB + 1), ssrc + 0 * (size_t)EB,
        dinvin + 0 * NB, W + 0 * D * D,
        x_dis,  dinvout + 2 * NB, offs + 2 * (NB + 1), ssrc + 2 * (size_t)EB,
        dinvin + 2 * NB, W + 2 * D * D,
        b + 0 * D, b + 2 * D, pa, (float*)d_out);

    // dst = dis: relation ds (A: x_drug,W1,b1) + relation ss (B: x_dis,W3,b3)
    k_fused<<<nblk, 256, 0, stream>>>(
        x_drug, dinvout + 1 * NB, offs + 1 * (NB + 1), ssrc + 1 * (size_t)EB,
        dinvin + 1 * NB, W + 1 * D * D,
        x_dis,  dinvout + 3 * NB, offs + 3 * (NB + 1), ssrc + 3 * (size_t)EB,
        dinvin + 3 * NB, W + 3 * D * D,
        b + 1 * D, b + 3 * D, pa, (float*)d_out + (size_t)NB * D);
}

// Round 2
// 688.019 us; speedup vs baseline: 1.2650x; 1.2650x over previous
//
#include <hip/hip_runtime.h>

// Node_Embedding: HeteroGraphConv(sum) of 4 GraphConv relations + PReLU.
// out_dsttype = (segsum(coef[e] * x[src[e]]) * degin^-1/2) @ W_A + ... + b.
// CSR-by-dst via counting sort; per-edge packed (src, degout^-1/2) int2;
// fused gather + [16,256]@[256,128] GEMM + bias + PReLU, both dst types in
// one dispatch (gridDim.y).

#define NB 50000   // nodes per type
#define EB 500000  // edges per relation
#define D  128

struct EdgePtrs { const int* src[4]; const int* dst[4]; };

__global__ void k_degrees(EdgePtrs ep, int* __restrict__ cntout, int* __restrict__ cntin) {
    int e = blockIdx.x * blockDim.x + threadIdx.x;
    int r = blockIdx.y;
    if (e < EB) {
        atomicAdd(&cntout[r * NB + ep.src[r][e]], 1);
        atomicAdd(&cntin[r * NB + ep.dst[r][e]], 1);
    }
}

// Exclusive scan of in-degree counts -> CSR offsets, plus a second copy used
// as the atomic fill cursor. One block per relation.
__global__ __launch_bounds__(1024) void k_scan(const int* __restrict__ cntin,
                                               int* __restrict__ offs,
                                               int* __restrict__ cursor) {
    int r = blockIdx.x;
    const int* cnt = cntin + r * NB;
    int* o = offs + r * (NB + 1);
    int* cu = cursor + r * NB;
    __shared__ int part[1024];
    int t = threadIdx.x;
    const int CH = (NB + 1023) / 1024;  // 49
    int lo = t * CH, hi = lo + CH; if (hi > NB) hi = NB;
    int s = 0;
    for (int i = lo; i < hi; ++i) s += cnt[i];
    part[t] = s;
    __syncthreads();
    for (int off = 1; off < 1024; off <<= 1) {
        int v = (t >= off) ? part[t - off] : 0;
        __syncthreads();
        part[t] += v;
        __syncthreads();
    }
    int run = (t == 0) ? 0 : part[t - 1];
    for (int i = lo; i < hi; ++i) { o[i] = run; cu[i] = run; run += cnt[i]; }
    if (t == 1023) o[NB] = part[1023];
}

// Scatter edges into CSR order, packing (src, degout^-1/2) per edge.
__global__ void k_fill(EdgePtrs ep, const int* __restrict__ cntout,
                       int* __restrict__ cursor, int2* __restrict__ epack) {
    int e = blockIdx.x * blockDim.x + threadIdx.x;
    int r = blockIdx.y;
    if (e < EB) {
        int s = ep.src[r][e], d = ep.dst[r][e];
        int c = cntout[r * NB + s];
        float coef = rsqrtf((float)(c > 1 ? c : 1));
        int pos = atomicAdd(&cursor[r * NB + d], 1);  // absolute CSR position
        epack[(size_t)r * EB + pos] = make_int2(s, __float_as_int(coef));
    }
}

// Fused gather + GEMM + bias + PReLU. blockIdx.y = dst node type t.
// Relations: A = t (src x_drug, W[t]), B = 2+t (src x_dis, W[2+t]).
// Block: 256 threads, 16 dst rows. Half-wave (32 lanes x float4) gathers one
// (row, rel) segment per round, 4 rounds/wave; 8-edge chunked prefetch.
__global__ __launch_bounds__(256) void k_fused(
    const float* __restrict__ x_drug, const float* __restrict__ x_dis,
    const float* __restrict__ W, const float* __restrict__ b,
    const float* __restrict__ prelu_a,
    const int* __restrict__ offs, const int2* __restrict__ epack,
    float* __restrict__ out) {
    __shared__ float slds[16][256];
    const int t = blockIdx.y;
    const int row0 = blockIdx.x * 16;
    const int tid = threadIdx.x;
    const int wavei = tid >> 6, lane = tid & 63;
    const int h = lane >> 5;               // half-wave: 0 -> rel A, 1 -> rel B
    const int c0 = (lane & 31) * 4;
    const int rA = t, rB = 2 + t;
    const int rel = h ? rB : rA;

    const int*  offsR = offs + rel * (NB + 1);
    const int2* epk   = epack + (size_t)rel * EB;
    const float* x    = h ? x_dis : x_drug;

    // ---- stage 1: gather ----
#pragma unroll
    for (int rr = 0; rr < 4; ++rr) {
        int rl = wavei * 4 + rr;
        int d = row0 + rl;
        int beg = offsR[d], end = offsR[d + 1];
        float4 a = make_float4(0.f, 0.f, 0.f, 0.f);
        for (int e = beg; e < end; e += 8) {
            int si[8]; float cf[8];
#pragma unroll
            for (int j = 0; j < 8; ++j) {
                int2 p = (e + j < end) ? epk[e + j] : make_int2(0, 0);
                si[j] = p.x; cf[j] = __int_as_float(p.y);
            }
            float4 xv[8];
#pragma unroll
            for (int j = 0; j < 8; ++j)
                xv[j] = *reinterpret_cast<const float4*>(x + (size_t)si[j] * D + c0);
#pragma unroll
            for (int j = 0; j < 8; ++j) {
                a.x = fmaf(xv[j].x, cf[j], a.x);
                a.y = fmaf(xv[j].y, cf[j], a.y);
                a.z = fmaf(xv[j].z, cf[j], a.z);
                a.w = fmaf(xv[j].w, cf[j], a.w);
            }
        }
        int dg = end - beg;
        float di = rsqrtf((float)(dg > 1 ? dg : 1));
        a.x *= di; a.y *= di; a.z *= di; a.w *= di;
        *reinterpret_cast<float4*>(&slds[rl][h * 128 + c0]) = a;
    }
    __syncthreads();

    // ---- stage 2: GEMM [16,256] @ [256,128] ----
    const int j0 = (tid & 31) * 4, r0 = (tid >> 5) * 2;
    const float* WA = W + rA * D * D;
    const float* WB = W + rB * D * D;
    float acc[2][4] = {{0.f, 0.f, 0.f, 0.f}, {0.f, 0.f, 0.f, 0.f}};
#pragma unroll 2
    for (int k0 = 0; k0 < 128; k0 += 4) {
        float4 s0 = *reinterpret_cast<const float4*>(&slds[r0][k0]);
        float4 s1 = *reinterpret_cast<const float4*>(&slds[r0 + 1][k0]);
#pragma unroll
        for (int kk = 0; kk < 4; ++kk) {
            float4 w = *reinterpret_cast<const float4*>(WA + (k0 + kk) * D + j0);
            float e0 = (&s0.x)[kk], e1 = (&s1.x)[kk];
            acc[0][0] = fmaf(e0, w.x, acc[0][0]);
            acc[0][1] = fmaf(e0, w.y, acc[0][1]);
            acc[0][2] = fmaf(e0, w.z, acc[0][2]);
            acc[0][3] = fmaf(e0, w.w, acc[0][3]);
            acc[1][0] = fmaf(e1, w.x, acc[1][0]);
            acc[1][1] = fmaf(e1, w.y, acc[1][1]);
            acc[1][2] = fmaf(e1, w.z, acc[1][2]);
            acc[1][3] = fmaf(e1, w.w, acc[1][3]);
        }
    }
#pragma unroll 2
    for (int k0 = 0; k0 < 128; k0 += 4) {
        float4 s0 = *reinterpret_cast<const float4*>(&slds[r0][128 + k0]);
        float4 s1 = *reinterpret_cast<const float4*>(&slds[r0 + 1][128 + k0]);
#pragma unroll
        for (int kk = 0; kk < 4; ++kk) {
            float4 w = *reinterpret_cast<const float4*>(WB + (k0 + kk) * D + j0);
            float e0 = (&s0.x)[kk], e1 = (&s1.x)[kk];
            acc[0][0] = fmaf(e0, w.x, acc[0][0]);
            acc[0][1] = fmaf(e0, w.y, acc[0][1]);
            acc[0][2] = fmaf(e0, w.z, acc[0][2]);
            acc[0][3] = fmaf(e0, w.w, acc[0][3]);
            acc[1][0] = fmaf(e1, w.x, acc[1][0]);
            acc[1][1] = fmaf(e1, w.y, acc[1][1]);
            acc[1][2] = fmaf(e1, w.z, acc[1][2]);
            acc[1][3] = fmaf(e1, w.w, acc[1][3]);
        }
    }

    // ---- epilogue: bias + PReLU + store ----
    float pa = prelu_a[0];
    const float* bA = b + rA * D;
    const float* bB = b + rB * D;
    float4 bb;
    bb.x = bA[j0 + 0] + bB[j0 + 0];
    bb.y = bA[j0 + 1] + bB[j0 + 1];
    bb.z = bA[j0 + 2] + bB[j0 + 2];
    bb.w = bA[j0 + 3] + bB[j0 + 3];
    float* o = out + (size_t)t * NB * D;
#pragma unroll
    for (int i = 0; i < 2; ++i) {
        float4 v;
        v.x = acc[i][0] + bb.x;
        v.y = acc[i][1] + bb.y;
        v.z = acc[i][2] + bb.z;
        v.w = acc[i][3] + bb.w;
        v.x = v.x >= 0.f ? v.x : pa * v.x;
        v.y = v.y >= 0.f ? v.y : pa * v.y;
        v.z = v.z >= 0.f ? v.z : pa * v.z;
        v.w = v.w >= 0.f ? v.w : pa * v.w;
        *reinterpret_cast<float4*>(o + (size_t)(row0 + r0 + i) * D + j0) = v;
    }
}

extern "C" void kernel_launch(void* const* d_in, const int* in_sizes, int n_in,
                              void* d_out, int out_size, void* d_ws, size_t ws_size,
                              hipStream_t stream) {
    const float* x_drug = (const float*)d_in[0];
    const float* x_dis  = (const float*)d_in[1];
    const float* W      = (const float*)d_in[2];   // [4,128,128]
    const float* b      = (const float*)d_in[3];   // [4,128]
    const float* pa     = (const float*)d_in[4];   // [1]
    EdgePtrs ep;
    ep.src[0] = (const int*)d_in[5];  ep.dst[0] = (const int*)d_in[6];   // dd
    ep.src[1] = (const int*)d_in[7];  ep.dst[1] = (const int*)d_in[8];   // ds
    ep.src[2] = (const int*)d_in[9];  ep.dst[2] = (const int*)d_in[10];  // sd
    ep.src[3] = (const int*)d_in[11]; ep.dst[3] = (const int*)d_in[12];  // ss

    // workspace layout (bytes)
    char* ws = (char*)d_ws;
    int*  cntout = (int*)(ws + 0);        // 4*NB ints (800000 B)
    int*  cntin  = (int*)(ws + 800000);   // 4*NB ints
    int*  offs   = (int*)(ws + 1600000);  // 4*(NB+1) ints (800016 B)
    int*  cursor = (int*)(ws + 2400064);  // 4*NB ints
    int2* epack  = (int2*)(ws + 3200064); // 4*EB int2 (16 MB) -> total ~19.2 MB

    hipMemsetAsync(ws, 0, 1600000, stream);  // cntout, cntin

    dim3 gE((EB + 255) / 256, 4);
    k_degrees<<<gE, 256, 0, stream>>>(ep, cntout, cntin);
    k_scan<<<4, 1024, 0, stream>>>(cntin, offs, cursor);
    k_fill<<<gE, 256, 0, stream>>>(ep, cntout, cursor, epack);
    k_fused<<<dim3(NB / 16, 2), 256, 0, stream>>>(
        x_drug, x_dis, W, b, pa, offs, epack, (float*)d_out);
}

// Round 3
// 577.614 us; speedup vs baseline: 1.5068x; 1.1911x over previous
//
#include <hip/hip_runtime.h>

// Node_Embedding: HeteroGraphConv(sum) of 4 GraphConv relations + PReLU.
// out_dsttype = (segsum(coef[e] * x[src[e]]) * degin^-1/2) @ W_A + ... + b.
// CSR-by-dst via counting sort; x pre-converted to bf16 to halve gather
// bytes; fused gather + [16,256]@[256,128] fp32 GEMM + bias + PReLU.

#define NB 50000   // nodes per type
#define EB 500000  // edges per relation
#define D  128
#define NCH 98     // ceil(NB/512)

struct EdgePtrs { const int* src[4]; const int* dst[4]; };

__device__ inline unsigned short f2bf(float f) {
    unsigned u = __float_as_uint(f);
    unsigned r = (u + 0x7FFFu + ((u >> 16) & 1u)) >> 16;  // RNE
    return (unsigned short)r;
}
__device__ inline float bf2f(unsigned short s) {
    return __uint_as_float((unsigned)s << 16);
}

__global__ __launch_bounds__(256) void k_degrees(EdgePtrs ep, int* __restrict__ cntout,
                                                 int* __restrict__ cntin) {
    int e = blockIdx.x * blockDim.x + threadIdx.x;
    int r = blockIdx.y;
    if (e < EB) {
        atomicAdd(&cntout[r * NB + ep.src[r][e]], 1);
        atomicAdd(&cntin[r * NB + ep.dst[r][e]], 1);
    }
}

// Convert x_drug,x_dis (fp32) -> bf16, flat over 2*NB*D elements, float4/thread.
__global__ __launch_bounds__(256) void k_cvt(const float* __restrict__ xd,
                                             const float* __restrict__ xs,
                                             unsigned short* __restrict__ xb) {
    int i = blockIdx.x * blockDim.x + threadIdx.x;   // float4 index
    const int TOT = 2 * NB * D / 4;                  // 3.2M
    if (i < TOT) {
        const int half = NB * D / 4;
        const float* src = (i < half) ? xd : xs;
        int j = (i < half) ? i : i - half;
        float4 v = reinterpret_cast<const float4*>(src)[j];
        ushort4 o;
        o.x = f2bf(v.x); o.y = f2bf(v.y); o.z = f2bf(v.z); o.w = f2bf(v.w);
        reinterpret_cast<ushort4*>(xb)[i] = o;
    }
}

// Phase 1: per-chunk (512 nodes) exclusive scan of in-degrees -> offs (local),
// chunk totals -> chunksum.
__global__ __launch_bounds__(512) void k_scan1(const int* __restrict__ cntin,
                                               int* __restrict__ offs,
                                               int* __restrict__ chunksum) {
    int r = blockIdx.y, c = blockIdx.x, t = threadIdx.x;
    int node = c * 512 + t;
    int v = (node < NB) ? cntin[r * NB + node] : 0;
    __shared__ int sh[512];
    sh[t] = v;
    __syncthreads();
    for (int off = 1; off < 512; off <<= 1) {
        int u = (t >= off) ? sh[t - off] : 0;
        __syncthreads();
        sh[t] += u;
        __syncthreads();
    }
    int incl = sh[t];
    if (node < NB) offs[r * (NB + 1) + node] = incl - v;  // local exclusive
    if (t == 511) chunksum[r * NCH + c] = incl;
}

// Phase 2: exclusive scan of the NCH chunk totals per relation (wave r).
__global__ __launch_bounds__(256) void k_scan2(int* __restrict__ chunksum) {
    int r = threadIdx.x >> 6, lane = threadIdx.x & 63;
    int* cs = chunksum + r * NCH;
    int s0 = cs[lane];
    int s1 = (64 + lane < NCH) ? cs[64 + lane] : 0;
    int x = s0;
    for (int d = 1; d < 64; d <<= 1) { int u = __shfl_up(x, d, 64); if (lane >= d) x += u; }
    int tot0 = __shfl(x, 63, 64);
    int y = s1;
    for (int d = 1; d < 64; d <<= 1) { int u = __shfl_up(y, d, 64); if (lane >= d) y += u; }
    y += tot0;
    cs[lane] = x - s0;
    if (64 + lane < NCH) cs[64 + lane] = y - s1;
}

// Phase 3: add chunk base; init cursor; offs[NB] = EB.
__global__ __launch_bounds__(512) void k_scan3(int* __restrict__ offs,
                                               int* __restrict__ cursor,
                                               const int* __restrict__ chunksum) {
    int r = blockIdx.y, c = blockIdx.x, t = threadIdx.x;
    int node = c * 512 + t;
    if (node < NB) {
        int v = offs[r * (NB + 1) + node] + chunksum[r * NCH + c];
        offs[r * (NB + 1) + node] = v;
        cursor[r * NB + node] = v;
    }
    if (c == NCH - 1 && t == 0) offs[r * (NB + 1) + NB] = EB;
}

// Scatter edges into CSR order, packing (src, degout^-1/2) per edge.
__global__ __launch_bounds__(256) void k_fill(EdgePtrs ep, const int* __restrict__ cntout,
                                              int* __restrict__ cursor,
                                              int2* __restrict__ epack) {
    int e = blockIdx.x * blockDim.x + threadIdx.x;
    int r = blockIdx.y;
    if (e < EB) {
        int s = ep.src[r][e], d = ep.dst[r][e];
        int c = cntout[r * NB + s];
        float coef = rsqrtf((float)(c > 1 ? c : 1));
        int pos = atomicAdd(&cursor[r * NB + d], 1);  // absolute CSR position
        epack[(size_t)r * EB + pos] = make_int2(s, __float_as_int(coef));
    }
}

// Fused gather(bf16) + GEMM + bias + PReLU. blockIdx.y = dst node type t.
// Relations: A = t (src x_drug, W[t]), B = 2+t (src x_dis, W[2+t]).
__global__ __launch_bounds__(256) void k_fused(
    const unsigned short* __restrict__ xb,  // [2][NB][D] bf16: drug then dis
    const float* __restrict__ W, const float* __restrict__ b,
    const float* __restrict__ prelu_a,
    const int* __restrict__ offs, const int2* __restrict__ epack,
    float* __restrict__ out) {
    __shared__ float slds[16][256];
    const int t = blockIdx.y;
    const int row0 = blockIdx.x * 16;
    const int tid = threadIdx.x;
    const int wavei = tid >> 6, lane = tid & 63;
    const int h = lane >> 5;               // half-wave: 0 -> rel A, 1 -> rel B
    const int c0 = (lane & 31) * 4;
    const int rA = t, rB = 2 + t;
    const int rel = h ? rB : rA;

    const int*  offsR = offs + rel * (NB + 1);
    const int2* epk   = epack + (size_t)rel * EB;
    const unsigned short* x = xb + (size_t)h * NB * D;

    // ---- stage 1: gather ----
#pragma unroll
    for (int rr = 0; rr < 4; ++rr) {
        int rl = wavei * 4 + rr;
        int d = row0 + rl;
        int beg = offsR[d], end = offsR[d + 1];
        float4 a = make_float4(0.f, 0.f, 0.f, 0.f);
        for (int e = beg; e < end; e += 8) {
            int si[8]; float cf[8];
#pragma unroll
            for (int j = 0; j < 8; ++j) {
                int2 p = (e + j < end) ? epk[e + j] : make_int2(0, 0);
                si[j] = p.x; cf[j] = __int_as_float(p.y);
            }
            ushort4 xv[8];
#pragma unroll
            for (int j = 0; j < 8; ++j)
                xv[j] = *reinterpret_cast<const ushort4*>(x + (size_t)si[j] * D + c0);
#pragma unroll
            for (int j = 0; j < 8; ++j) {
                a.x = fmaf(bf2f(xv[j].x), cf[j], a.x);
                a.y = fmaf(bf2f(xv[j].y), cf[j], a.y);
                a.z = fmaf(bf2f(xv[j].z), cf[j], a.z);
                a.w = fmaf(bf2f(xv[j].w), cf[j], a.w);
            }
        }
        int dg = end - beg;
        float di = rsqrtf((float)(dg > 1 ? dg : 1));
        a.x *= di; a.y *= di; a.z *= di; a.w *= di;
        *reinterpret_cast<float4*>(&slds[rl][h * 128 + c0]) = a;
    }
    __syncthreads();

    // ---- stage 2: GEMM [16,256] @ [256,128] ----
    const int j0 = (tid & 31) * 4, r0 = (tid >> 5) * 2;
    const float* WA = W + rA * D * D;
    const float* WB = W + rB * D * D;
    float acc[2][4] = {{0.f, 0.f, 0.f, 0.f}, {0.f, 0.f, 0.f, 0.f}};
#pragma unroll 2
    for (int k0 = 0; k0 < 128; k0 += 4) {
        float4 s0 = *reinterpret_cast<const float4*>(&slds[r0][k0]);
        float4 s1 = *reinterpret_cast<const float4*>(&slds[r0 + 1][k0]);
#pragma unroll
        for (int kk = 0; kk < 4; ++kk) {
            float4 w = *reinterpret_cast<const float4*>(WA + (k0 + kk) * D + j0);
            float e0 = (&s0.x)[kk], e1 = (&s1.x)[kk];
            acc[0][0] = fmaf(e0, w.x, acc[0][0]);
            acc[0][1] = fmaf(e0, w.y, acc[0][1]);
            acc[0][2] = fmaf(e0, w.z, acc[0][2]);
            acc[0][3] = fmaf(e0, w.w, acc[0][3]);
            acc[1][0] = fmaf(e1, w.x, acc[1][0]);
            acc[1][1] = fmaf(e1, w.y, acc[1][1]);
            acc[1][2] = fmaf(e1, w.z, acc[1][2]);
            acc[1][3] = fmaf(e1, w.w, acc[1][3]);
        }
    }
#pragma unroll 2
    for (int k0 = 0; k0 < 128; k0 += 4) {
        float4 s0 = *reinterpret_cast<const float4*>(&slds[r0][128 + k0]);
        float4 s1 = *reinterpret_cast<const float4*>(&slds[r0 + 1][128 + k0]);
#pragma unroll
        for (int kk = 0; kk < 4; ++kk) {
            float4 w = *reinterpret_cast<const float4*>(WB + (k0 + kk) * D + j0);
            float e0 = (&s0.x)[kk], e1 = (&s1.x)[kk];
            acc[0][0] = fmaf(e0, w.x, acc[0][0]);
            acc[0][1] = fmaf(e0, w.y, acc[0][1]);
            acc[0][2] = fmaf(e0, w.z, acc[0][2]);
            acc[0][3] = fmaf(e0, w.w, acc[0][3]);
            acc[1][0] = fmaf(e1, w.x, acc[1][0]);
            acc[1][1] = fmaf(e1, w.y, acc[1][1]);
            acc[1][2] = fmaf(e1, w.z, acc[1][2]);
            acc[1][3] = fmaf(e1, w.w, acc[1][3]);
        }
    }

    // ---- epilogue: bias + PReLU + store ----
    float pa = prelu_a[0];
    const float* bA = b + rA * D;
    const float* bB = b + rB * D;
    float4 bb;
    bb.x = bA[j0 + 0] + bB[j0 + 0];
    bb.y = bA[j0 + 1] + bB[j0 + 1];
    bb.z = bA[j0 + 2] + bB[j0 + 2];
    bb.w = bA[j0 + 3] + bB[j0 + 3];
    float* o = out + (size_t)t * NB * D;
#pragma unroll
    for (int i = 0; i < 2; ++i) {
        float4 v;
        v.x = acc[i][0] + bb.x;
        v.y = acc[i][1] + bb.y;
        v.z = acc[i][2] + bb.z;
        v.w = acc[i][3] + bb.w;
        v.x = v.x >= 0.f ? v.x : pa * v.x;
        v.y = v.y >= 0.f ? v.y : pa * v.y;
        v.z = v.z >= 0.f ? v.z : pa * v.z;
        v.w = v.w >= 0.f ? v.w : pa * v.w;
        *reinterpret_cast<float4*>(o + (size_t)(row0 + r0 + i) * D + j0) = v;
    }
}

extern "C" void kernel_launch(void* const* d_in, const int* in_sizes, int n_in,
                              void* d_out, int out_size, void* d_ws, size_t ws_size,
                              hipStream_t stream) {
    const float* x_drug = (const float*)d_in[0];
    const float* x_dis  = (const float*)d_in[1];
    const float* W      = (const float*)d_in[2];   // [4,128,128]
    const float* b      = (const float*)d_in[3];   // [4,128]
    const float* pa     = (const float*)d_in[4];   // [1]
    EdgePtrs ep;
    ep.src[0] = (const int*)d_in[5];  ep.dst[0] = (const int*)d_in[6];   // dd
    ep.src[1] = (const int*)d_in[7];  ep.dst[1] = (const int*)d_in[8];   // ds
    ep.src[2] = (const int*)d_in[9];  ep.dst[2] = (const int*)d_in[10];  // sd
    ep.src[3] = (const int*)d_in[11]; ep.dst[3] = (const int*)d_in[12];  // ss

    // workspace layout (bytes)
    char* ws = (char*)d_ws;
    int*  cntout   = (int*)(ws + 0);        // 4*NB ints
    int*  cntin    = (int*)(ws + 800000);   // 4*NB ints
    int*  offs     = (int*)(ws + 1600000);  // 4*(NB+1) ints
    int*  cursor   = (int*)(ws + 2400064);  // 4*NB ints
    int*  chunksum = (int*)(ws + 3200064);  // 4*NCH ints
    int2* epack    = (int2*)(ws + 3201664); // 4*EB int2 (16 MB)
    unsigned short* xb = (unsigned short*)(ws + 19201664); // 2*NB*D bf16 (25.6 MB)
    // total ~44.8 MB

    hipMemsetAsync(ws, 0, 1600000, stream);  // cntout, cntin

    dim3 gE((EB + 255) / 256, 4);
    k_degrees<<<gE, 256, 0, stream>>>(ep, cntout, cntin);
    k_cvt<<<(2 * NB * D / 4 + 255) / 256, 256, 0, stream>>>(x_drug, x_dis, xb);
    k_scan1<<<dim3(NCH, 4), 512, 0, stream>>>(cntin, offs, chunksum);
    k_scan2<<<1, 256, 0, stream>>>(chunksum);
    k_scan3<<<dim3(NCH, 4), 512, 0, stream>>>(offs, cursor, chunksum);
    k_fill<<<gE, 256, 0, stream>>>(ep, cntout, cursor, epack);
    k_fused<<<dim3(NB / 16, 2), 256, 0, stream>>>(
        xb, W, b, pa, offs, epack, (float*)d_out);
}

// Round 4
// 519.239 us; speedup vs baseline: 1.6762x; 1.1124x over previous
//
#include <hip/hip_runtime.h>

// Node_Embedding: HeteroGraphConv(sum) of 4 GraphConv relations + PReLU.
// out_dsttype = (segsum(coef[e] * x[src[e]]) * degin^-1/2) @ W_A + ... + b.
// CSR-by-dst via counting sort; x pre-converted to bf16; fused kernel stages
// each block's contiguous edge window into LDS (kills the epack->row-load
// dependency chain), gathers rows with 16-lane groups (4 rows in flight),
// then [16,256]@[256,128] fp32 GEMM + bias + PReLU.

#define NB 50000   // nodes per type
#define EB 500000  // edges per relation
#define D  128
#define NCH 98     // ceil(NB/512)

struct EdgePtrs { const int* src[4]; const int* dst[4]; };

__device__ inline unsigned short f2bf(float f) {
    unsigned u = __float_as_uint(f);
    unsigned r = (u + 0x7FFFu + ((u >> 16) & 1u)) >> 16;  // RNE
    return (unsigned short)r;
}
__device__ inline float blo(unsigned u) { return __uint_as_float(u << 16); }
__device__ inline float bhi(unsigned u) { return __uint_as_float(u & 0xffff0000u); }

__global__ __launch_bounds__(256) void k_degrees(EdgePtrs ep, int* __restrict__ cntout,
                                                 int* __restrict__ cntin) {
    int e = blockIdx.x * blockDim.x + threadIdx.x;
    int r = blockIdx.y;
    if (e < EB) {
        atomicAdd(&cntout[r * NB + ep.src[r][e]], 1);
        atomicAdd(&cntin[r * NB + ep.dst[r][e]], 1);
    }
}

// Convert x_drug,x_dis (fp32) -> bf16, flat over 2*NB*D elements, float4/thread.
__global__ __launch_bounds__(256) void k_cvt(const float* __restrict__ xd,
                                             const float* __restrict__ xs,
                                             unsigned short* __restrict__ xb) {
    int i = blockIdx.x * blockDim.x + threadIdx.x;   // float4 index
    const int TOT = 2 * NB * D / 4;                  // 3.2M
    if (i < TOT) {
        const int half = NB * D / 4;
        const float* src = (i < half) ? xd : xs;
        int j = (i < half) ? i : i - half;
        float4 v = reinterpret_cast<const float4*>(src)[j];
        ushort4 o;
        o.x = f2bf(v.x); o.y = f2bf(v.y); o.z = f2bf(v.z); o.w = f2bf(v.w);
        reinterpret_cast<ushort4*>(xb)[i] = o;
    }
}

// Phase 1: per-chunk (512 nodes) exclusive scan of in-degrees.
__global__ __launch_bounds__(512) void k_scan1(const int* __restrict__ cntin,
                                               int* __restrict__ offs,
                                               int* __restrict__ chunksum) {
    int r = blockIdx.y, c = blockIdx.x, t = threadIdx.x;
    int node = c * 512 + t;
    int v = (node < NB) ? cntin[r * NB + node] : 0;
    __shared__ int sh[512];
    sh[t] = v;
    __syncthreads();
    for (int off = 1; off < 512; off <<= 1) {
        int u = (t >= off) ? sh[t - off] : 0;
        __syncthreads();
        sh[t] += u;
        __syncthreads();
    }
    int incl = sh[t];
    if (node < NB) offs[r * (NB + 1) + node] = incl - v;  // local exclusive
    if (t == 511) chunksum[r * NCH + c] = incl;
}

// Phase 2: exclusive scan of the NCH chunk totals per relation (wave r).
__global__ __launch_bounds__(256) void k_scan2(int* __restrict__ chunksum) {
    int r = threadIdx.x >> 6, lane = threadIdx.x & 63;
    int* cs = chunksum + r * NCH;
    int s0 = cs[lane];
    int s1 = (64 + lane < NCH) ? cs[64 + lane] : 0;
    int x = s0;
    for (int d = 1; d < 64; d <<= 1) { int u = __shfl_up(x, d, 64); if (lane >= d) x += u; }
    int tot0 = __shfl(x, 63, 64);
    int y = s1;
    for (int d = 1; d < 64; d <<= 1) { int u = __shfl_up(y, d, 64); if (lane >= d) y += u; }
    y += tot0;
    cs[lane] = x - s0;
    if (64 + lane < NCH) cs[64 + lane] = y - s1;
}

// Phase 3: add chunk base; init cursor; offs[NB] = EB.
__global__ __launch_bounds__(512) void k_scan3(int* __restrict__ offs,
                                               int* __restrict__ cursor,
                                               const int* __restrict__ chunksum) {
    int r = blockIdx.y, c = blockIdx.x, t = threadIdx.x;
    int node = c * 512 + t;
    if (node < NB) {
        int v = offs[r * (NB + 1) + node] + chunksum[r * NCH + c];
        offs[r * (NB + 1) + node] = v;
        cursor[r * NB + node] = v;
    }
    if (c == NCH - 1 && t == 0) offs[r * (NB + 1) + NB] = EB;
}

// Scatter edges into CSR order, packing (src, degout^-1/2) per edge.
__global__ __launch_bounds__(256) void k_fill(EdgePtrs ep, const int* __restrict__ cntout,
                                              int* __restrict__ cursor,
                                              int2* __restrict__ epack) {
    int e = blockIdx.x * blockDim.x + threadIdx.x;
    int r = blockIdx.y;
    if (e < EB) {
        int s = ep.src[r][e], d = ep.dst[r][e];
        int c = cntout[r * NB + s];
        float coef = rsqrtf((float)(c > 1 ? c : 1));
        int pos = atomicAdd(&cursor[r * NB + d], 1);  // absolute CSR position
        epack[(size_t)r * EB + pos] = make_int2(s, __float_as_int(coef));
    }
}

// Fused gather(bf16) + GEMM + bias + PReLU. blockIdx.y = dst node type t.
// Relations: A = t (src x_drug half), B = 2+t (src x_dis half).
__global__ __launch_bounds__(256) void k_fused(
    const unsigned short* __restrict__ xb,  // [2][NB][D] bf16: drug then dis
    const float* __restrict__ W, const float* __restrict__ b,
    const float* __restrict__ prelu_a,
    const int* __restrict__ offs, const int2* __restrict__ epack,
    float* __restrict__ out) {
    __shared__ float S[16][256];
    __shared__ int2 ebuf[256];
    __shared__ int soff[2][17];
    const int t = blockIdx.y;
    const int row0 = blockIdx.x * 16;
    const int tid = threadIdx.x;
    const int g = tid >> 4, l16 = tid & 15;
    const int cbase = l16 * 8;          // this lane's 8 bf16 columns

    if (tid < 34) {
        int h = tid / 17, k = tid % 17;
        int rel = h ? (2 + t) : t;
        soff[h][k] = offs[rel * (NB + 1) + row0 + k];
    }
    __syncthreads();

    // ---- stage 1: per-relation LDS-staged gather ----
    for (int h = 0; h < 2; ++h) {
        int rel = h ? (2 + t) : t;
        const unsigned short* x = xb + (size_t)h * NB * D;
        const int2* epk = epack + (size_t)rel * EB;
        const int base = soff[h][0];
        const int total = soff[h][16] - base;
        const int glo = soff[h][g] - base;
        const int ghi = soff[h][g + 1] - base;
        float acc[8] = {0.f, 0.f, 0.f, 0.f, 0.f, 0.f, 0.f, 0.f};

        for (int tile = 0; tile < total; tile += 256) {
            int n = total - tile; if (n > 256) n = 256;
            __syncthreads();   // previous ebuf consumers done
            if (tid < n) ebuf[tid] = epk[base + tile + tid];
            __syncthreads();
            int lo = glo - tile; if (lo < 0) lo = 0;
            int hi = ghi - tile; if (hi > n) hi = n;
            for (int i = lo; i < hi; i += 4) {
                int i1 = i + 1 < hi ? i + 1 : hi - 1;
                int i2 = i + 2 < hi ? i + 2 : hi - 1;
                int i3 = i + 3 < hi ? i + 3 : hi - 1;
                int2 p0 = ebuf[i], p1 = ebuf[i1], p2 = ebuf[i2], p3 = ebuf[i3];
                float c0 = __int_as_float(p0.y);
                float c1 = (i + 1 < hi) ? __int_as_float(p1.y) : 0.f;
                float c2 = (i + 2 < hi) ? __int_as_float(p2.y) : 0.f;
                float c3 = (i + 3 < hi) ? __int_as_float(p3.y) : 0.f;
                uint4 r0 = *reinterpret_cast<const uint4*>(x + (size_t)p0.x * D + cbase);
                uint4 r1 = *reinterpret_cast<const uint4*>(x + (size_t)p1.x * D + cbase);
                uint4 r2 = *reinterpret_cast<const uint4*>(x + (size_t)p2.x * D + cbase);
                uint4 r3 = *reinterpret_cast<const uint4*>(x + (size_t)p3.x * D + cbase);
                acc[0] = fmaf(blo(r0.x), c0, acc[0]); acc[1] = fmaf(bhi(r0.x), c0, acc[1]);
                acc[2] = fmaf(blo(r0.y), c0, acc[2]); acc[3] = fmaf(bhi(r0.y), c0, acc[3]);
                acc[4] = fmaf(blo(r0.z), c0, acc[4]); acc[5] = fmaf(bhi(r0.z), c0, acc[5]);
                acc[6] = fmaf(blo(r0.w), c0, acc[6]); acc[7] = fmaf(bhi(r0.w), c0, acc[7]);
                acc[0] = fmaf(blo(r1.x), c1, acc[0]); acc[1] = fmaf(bhi(r1.x), c1, acc[1]);
                acc[2] = fmaf(blo(r1.y), c1, acc[2]); acc[3] = fmaf(bhi(r1.y), c1, acc[3]);
                acc[4] = fmaf(blo(r1.z), c1, acc[4]); acc[5] = fmaf(bhi(r1.z), c1, acc[5]);
                acc[6] = fmaf(blo(r1.w), c1, acc[6]); acc[7] = fmaf(bhi(r1.w), c1, acc[7]);
                acc[0] = fmaf(blo(r2.x), c2, acc[0]); acc[1] = fmaf(bhi(r2.x), c2, acc[1]);
                acc[2] = fmaf(blo(r2.y), c2, acc[2]); acc[3] = fmaf(bhi(r2.y), c2, acc[3]);
                acc[4] = fmaf(blo(r2.z), c2, acc[4]); acc[5] = fmaf(bhi(r2.z), c2, acc[5]);
                acc[6] = fmaf(blo(r2.w), c2, acc[6]); acc[7] = fmaf(bhi(r2.w), c2, acc[7]);
                acc[0] = fmaf(blo(r3.x), c3, acc[0]); acc[1] = fmaf(bhi(r3.x), c3, acc[1]);
                acc[2] = fmaf(blo(r3.y), c3, acc[2]); acc[3] = fmaf(bhi(r3.y), c3, acc[3]);
                acc[4] = fmaf(blo(r3.z), c3, acc[4]); acc[5] = fmaf(bhi(r3.z), c3, acc[5]);
                acc[6] = fmaf(blo(r3.w), c3, acc[6]); acc[7] = fmaf(bhi(r3.w), c3, acc[7]);
            }
        }
        int dg = ghi - glo;
        float di = rsqrtf((float)(dg > 1 ? dg : 1));
#pragma unroll
        for (int k = 0; k < 8; ++k) acc[k] *= di;
        float4 v0 = make_float4(acc[0], acc[1], acc[2], acc[3]);
        float4 v1 = make_float4(acc[4], acc[5], acc[6], acc[7]);
        *reinterpret_cast<float4*>(&S[g][h * 128 + cbase]) = v0;
        *reinterpret_cast<float4*>(&S[g][h * 128 + cbase + 4]) = v1;
    }
    __syncthreads();

    // ---- stage 2: GEMM [16,256] @ [256,128] ----
    const int rA = t, rB = 2 + t;
    const int j0 = (tid & 31) * 4, r0i = (tid >> 5) * 2;
    const float* WA = W + rA * D * D;
    const float* WB = W + rB * D * D;
    float acc2[2][4] = {{0.f, 0.f, 0.f, 0.f}, {0.f, 0.f, 0.f, 0.f}};
#pragma unroll 2
    for (int k0 = 0; k0 < 128; k0 += 4) {
        float4 s0 = *reinterpret_cast<const float4*>(&S[r0i][k0]);
        float4 s1 = *reinterpret_cast<const float4*>(&S[r0i + 1][k0]);
#pragma unroll
        for (int kk = 0; kk < 4; ++kk) {
            float4 w = *reinterpret_cast<const float4*>(WA + (k0 + kk) * D + j0);
            float e0 = (&s0.x)[kk], e1 = (&s1.x)[kk];
            acc2[0][0] = fmaf(e0, w.x, acc2[0][0]);
            acc2[0][1] = fmaf(e0, w.y, acc2[0][1]);
            acc2[0][2] = fmaf(e0, w.z, acc2[0][2]);
            acc2[0][3] = fmaf(e0, w.w, acc2[0][3]);
            acc2[1][0] = fmaf(e1, w.x, acc2[1][0]);
            acc2[1][1] = fmaf(e1, w.y, acc2[1][1]);
            acc2[1][2] = fmaf(e1, w.z, acc2[1][2]);
            acc2[1][3] = fmaf(e1, w.w, acc2[1][3]);
        }
    }
#pragma unroll 2
    for (int k0 = 0; k0 < 128; k0 += 4) {
        float4 s0 = *reinterpret_cast<const float4*>(&S[r0i][128 + k0]);
        float4 s1 = *reinterpret_cast<const float4*>(&S[r0i + 1][128 + k0]);
#pragma unroll
        for (int kk = 0; kk < 4; ++kk) {
            float4 w = *reinterpret_cast<const float4*>(WB + (k0 + kk) * D + j0);
            float e0 = (&s0.x)[kk], e1 = (&s1.x)[kk];
            acc2[0][0] = fmaf(e0, w.x, acc2[0][0]);
            acc2[0][1] = fmaf(e0, w.y, acc2[0][1]);
            acc2[0][2] = fmaf(e0, w.z, acc2[0][2]);
            acc2[0][3] = fmaf(e0, w.w, acc2[0][3]);
            acc2[1][0] = fmaf(e1, w.x, acc2[1][0]);
            acc2[1][1] = fmaf(e1, w.y, acc2[1][1]);
            acc2[1][2] = fmaf(e1, w.z, acc2[1][2]);
            acc2[1][3] = fmaf(e1, w.w, acc2[1][3]);
        }
    }

    // ---- epilogue: bias + PReLU + store ----
    float pa = prelu_a[0];
    const float* bA = b + rA * D;
    const float* bB = b + rB * D;
    float4 bb;
    bb.x = bA[j0 + 0] + bB[j0 + 0];
    bb.y = bA[j0 + 1] + bB[j0 + 1];
    bb.z = bA[j0 + 2] + bB[j0 + 2];
    bb.w = bA[j0 + 3] + bB[j0 + 3];
    float* o = out + (size_t)t * NB * D;
#pragma unroll
    for (int i = 0; i < 2; ++i) {
        float4 v;
        v.x = acc2[i][0] + bb.x;
        v.y = acc2[i][1] + bb.y;
        v.z = acc2[i][2] + bb.z;
        v.w = acc2[i][3] + bb.w;
        v.x = v.x >= 0.f ? v.x : pa * v.x;
        v.y = v.y >= 0.f ? v.y : pa * v.y;
        v.z = v.z >= 0.f ? v.z : pa * v.z;
        v.w = v.w >= 0.f ? v.w : pa * v.w;
        *reinterpret_cast<float4*>(o + (size_t)(row0 + r0i + i) * D + j0) = v;
    }
}

extern "C" void kernel_launch(void* const* d_in, const int* in_sizes, int n_in,
                              void* d_out, int out_size, void* d_ws, size_t ws_size,
                              hipStream_t stream) {
    const float* x_drug = (const float*)d_in[0];
    const float* x_dis  = (const float*)d_in[1];
    const float* W      = (const float*)d_in[2];   // [4,128,128]
    const float* b      = (const float*)d_in[3];   // [4,128]
    const float* pa     = (const float*)d_in[4];   // [1]
    EdgePtrs ep;
    ep.src[0] = (const int*)d_in[5];  ep.dst[0] = (const int*)d_in[6];   // dd
    ep.src[1] = (const int*)d_in[7];  ep.dst[1] = (const int*)d_in[8];   // ds
    ep.src[2] = (const int*)d_in[9];  ep.dst[2] = (const int*)d_in[10];  // sd
    ep.src[3] = (const int*)d_in[11]; ep.dst[3] = (const int*)d_in[12];  // ss

    // workspace layout (bytes)
    char* ws = (char*)d_ws;
    int*  cntout   = (int*)(ws + 0);        // 4*NB ints
    int*  cntin    = (int*)(ws + 800000);   // 4*NB ints
    int*  offs     = (int*)(ws + 1600000);  // 4*(NB+1) ints
    int*  cursor   = (int*)(ws + 2400064);  // 4*NB ints
    int*  chunksum = (int*)(ws + 3200064);  // 4*NCH ints
    int2* epack    = (int2*)(ws + 3201664); // 4*EB int2 (16 MB)
    unsigned short* xb = (unsigned short*)(ws + 19201664); // 2*NB*D bf16 (25.6 MB)
    // total ~44.8 MB

    hipMemsetAsync(ws, 0, 1600000, stream);  // cntout, cntin

    dim3 gE((EB + 255) / 256, 4);
    k_degrees<<<gE, 256, 0, stream>>>(ep, cntout, cntin);
    k_cvt<<<(2 * NB * D / 4 + 255) / 256, 256, 0, stream>>>(x_drug, x_dis, xb);
    k_scan1<<<dim3(NCH, 4), 512, 0, stream>>>(cntin, offs, chunksum);
    k_scan2<<<1, 256, 0, stream>>>(chunksum);
    k_scan3<<<dim3(NCH, 4), 512, 0, stream>>>(offs, cursor, chunksum);
    k_fill<<<gE, 256, 0, stream>>>(ep, cntout, cursor, epack);
    k_fused<<<dim3(NB / 16, 2), 256, 0, stream>>>(
        xb, W, b, pa, offs, epack, (float*)d_out);
}

// Round 6
// 442.112 us; speedup vs baseline: 1.9687x; 1.1745x over previous
//
#include <hip/hip_runtime.h>

// Node_Embedding: HeteroGraphConv(sum) of 4 GraphConv relations + PReLU.
// out_dsttype = (segsum(coef[e] * x[src[e]]) * degin^-1/2) @ W_A + ... + b.
// CSR-by-dst via counting sort (rank captured from the degree atomic, so the
// fill pass has no atomics); x pre-converted to bf16; fused kernel stages
// both relations' edge windows in LDS and runs a software-pipelined
// (8-edge double-buffered) gather, then [16,256]@[256,128] fp32 GEMM.

#define NB 50000   // nodes per type
#define EB 500000  // edges per relation
#define D  128
#define NCH 98     // ceil(NB/512)
#define DEGBLK 1954  // ceil(EB/256)
#define CVTBLK 3125  // 12500 cvt blocks total / 4 (one share per blockIdx.y)
#define CAP 512      // LDS edge-window capacity per relation (mean 160)

struct EdgePtrs { const int* src[4]; const int* dst[4]; };

__device__ inline unsigned short f2bf(float f) {
    unsigned u = __float_as_uint(f);
    unsigned r = (u + 0x7FFFu + ((u >> 16) & 1u)) >> 16;  // RNE
    return (unsigned short)r;
}
__device__ inline float blo(unsigned u) { return __uint_as_float(u << 16); }
__device__ inline float bhi(unsigned u) { return __uint_as_float(u & 0xffff0000u); }

// Fused: per-relation degree histograms (rank captured) + x -> bf16 convert.
__global__ __launch_bounds__(256) void k_deg_cvt(
    EdgePtrs ep, int* __restrict__ cntout, int* __restrict__ cntin,
    int* __restrict__ rank,
    const float* __restrict__ xd, const float* __restrict__ xs,
    unsigned short* __restrict__ xb) {
    int bx = blockIdx.x, r = blockIdx.y, tid = threadIdx.x;
    if (bx < DEGBLK) {
        int e = bx * 256 + tid;
        if (e < EB) {
            int s = ep.src[r][e], d = ep.dst[r][e];
            atomicAdd(&cntout[r * NB + s], 1);
            rank[(size_t)r * EB + e] = atomicAdd(&cntin[r * NB + d], 1);
        }
    } else {
        int c = (bx - DEGBLK) + CVTBLK * r;       // 0..12499
        if (c < 2 * NB * D / 1024) {
            int i = c * 256 + tid;                 // float4 index
            const int half = NB * D / 4;
            const float* src = (i < half) ? xd : xs;
            int j = (i < half) ? i : i - half;
            float4 v = reinterpret_cast<const float4*>(src)[j];
            ushort4 o;
            o.x = f2bf(v.x); o.y = f2bf(v.y); o.z = f2bf(v.z); o.w = f2bf(v.w);
            reinterpret_cast<ushort4*>(xb)[i] = o;
        }
    }
}

// Phase 1: per-chunk (512 nodes) exclusive scan of in-degrees.
__global__ __launch_bounds__(512) void k_scan1(const int* __restrict__ cntin,
                                               int* __restrict__ offs,
                                               int* __restrict__ chunksum) {
    int r = blockIdx.y, c = blockIdx.x, t = threadIdx.x;
    int node = c * 512 + t;
    int v = (node < NB) ? cntin[r * NB + node] : 0;
    __shared__ int sh[512];
    sh[t] = v;
    __syncthreads();
    for (int off = 1; off < 512; off <<= 1) {
        int u = (t >= off) ? sh[t - off] : 0;
        __syncthreads();
        sh[t] += u;
        __syncthreads();
    }
    int incl = sh[t];
    if (node < NB) offs[r * (NB + 1) + node] = incl - v;  // local exclusive
    if (t == 511) chunksum[r * NCH + c] = incl;
}

// Phase 2: exclusive scan of the NCH chunk totals per relation (wave r).
__global__ __launch_bounds__(256) void k_scan2(int* __restrict__ chunksum) {
    int r = threadIdx.x >> 6, lane = threadIdx.x & 63;
    int* cs = chunksum + r * NCH;
    int s0 = cs[lane];
    int s1 = (64 + lane < NCH) ? cs[64 + lane] : 0;
    int x = s0;
    for (int d = 1; d < 64; d <<= 1) { int u = __shfl_up(x, d, 64); if (lane >= d) x += u; }
    int tot0 = __shfl(x, 63, 64);
    int y = s1;
    for (int d = 1; d < 64; d <<= 1) { int u = __shfl_up(y, d, 64); if (lane >= d) y += u; }
    y += tot0;
    cs[lane] = x - s0;
    if (64 + lane < NCH) cs[64 + lane] = y - s1;
}

// Phase 3: add chunk base; offs[NB] = EB.
__global__ __launch_bounds__(512) void k_scan3(int* __restrict__ offs,
                                               const int* __restrict__ chunksum) {
    int r = blockIdx.y, c = blockIdx.x, t = threadIdx.x;
    int node = c * 512 + t;
    if (node < NB)
        offs[r * (NB + 1) + node] += chunksum[r * NCH + c];
    if (c == NCH - 1 && t == 0) offs[r * (NB + 1) + NB] = EB;
}

// Scatter edges into CSR order via precomputed rank (no atomics).
__global__ __launch_bounds__(256) void k_fill(EdgePtrs ep, const int* __restrict__ cntout,
                                              const int* __restrict__ offs,
                                              const int* __restrict__ rank,
                                              int2* __restrict__ epack) {
    int e = blockIdx.x * blockDim.x + threadIdx.x;
    int r = blockIdx.y;
    if (e < EB) {
        int s = ep.src[r][e], d = ep.dst[r][e];
        int c = cntout[r * NB + s];
        float coef = rsqrtf((float)(c > 1 ? c : 1));
        int pos = offs[r * (NB + 1) + d] + rank[(size_t)r * EB + e];
        epack[(size_t)r * EB + pos] = make_int2(s, __float_as_int(coef));
    }
}

#define PREF(ii, c0, c1, c2, c3, r0, r1, r2, r3)                               \
    {                                                                          \
        int j1 = (ii) + 1 < ghi ? (ii) + 1 : ghi - 1;                          \
        int j2 = (ii) + 2 < ghi ? (ii) + 2 : ghi - 1;                          \
        int j3 = (ii) + 3 < ghi ? (ii) + 3 : ghi - 1;                          \
        int2 q0 = eb[(ii)], q1 = eb[j1], q2 = eb[j2], q3 = eb[j3];             \
        c0 = __int_as_float(q0.y);                                             \
        c1 = ((ii) + 1 < ghi) ? __int_as_float(q1.y) : 0.f;                    \
        c2 = ((ii) + 2 < ghi) ? __int_as_float(q2.y) : 0.f;                    \
        c3 = ((ii) + 3 < ghi) ? __int_as_float(q3.y) : 0.f;                    \
        r0 = *reinterpret_cast<const uint4*>(x + ((unsigned)q0.x * D + cbase));\
        r1 = *reinterpret_cast<const uint4*>(x + ((unsigned)q1.x * D + cbase));\
        r2 = *reinterpret_cast<const uint4*>(x + ((unsigned)q2.x * D + cbase));\
        r3 = *reinterpret_cast<const uint4*>(x + ((unsigned)q3.x * D + cbase));\
    }

#define FMA8(c, r)                                                             \
    {                                                                          \
        acc[0] = fmaf(blo(r.x), c, acc[0]); acc[1] = fmaf(bhi(r.x), c, acc[1]);\
        acc[2] = fmaf(blo(r.y), c, acc[2]); acc[3] = fmaf(bhi(r.y), c, acc[3]);\
        acc[4] = fmaf(blo(r.z), c, acc[4]); acc[5] = fmaf(bhi(r.z), c, acc[5]);\
        acc[6] = fmaf(blo(r.w), c, acc[6]); acc[7] = fmaf(bhi(r.w), c, acc[7]);\
    }

// Fused gather(bf16, pipelined) + GEMM + bias + PReLU. blockIdx.y = dst type.
__global__ __launch_bounds__(256) void k_fused(
    const unsigned short* __restrict__ xb,  // [2][NB][D] bf16: drug then dis
    const float* __restrict__ W, const float* __restrict__ b,
    const float* __restrict__ prelu_a,
    const int* __restrict__ offs, const int2* __restrict__ epack,
    float* __restrict__ out) {
    __shared__ float S[16][256];
    __shared__ int2 ebuf[2][CAP];
    __shared__ int soff[2][17];
    const int t = blockIdx.y;
    const int row0 = blockIdx.x * 16;
    const int tid = threadIdx.x;
    const int g = tid >> 4, l16 = tid & 15;
    const int cbase = l16 * 8;          // this lane's 8 bf16 columns

    if (tid < 34) {
        int h = tid / 17, k = tid % 17;
        int rel = h ? (2 + t) : t;
        soff[h][k] = offs[rel * (NB + 1) + row0 + k];
    }
    __syncthreads();

    // stage both relations' edge windows (first CAP each)
    for (int h = 0; h < 2; ++h) {
        int rel = h ? (2 + t) : t;
        const int2* epk = epack + (size_t)rel * EB;
        int base = soff[h][0];
        int tot = soff[h][16] - base; if (tot > CAP) tot = CAP;
        for (int i = tid; i < tot; i += 256) ebuf[h][i] = epk[base + i];
    }
    __syncthreads();

    // ---- stage 1: pipelined gather ----
    for (int h = 0; h < 2; ++h) {
        int rel = h ? (2 + t) : t;
        const unsigned short* x = xb + (size_t)h * NB * D;
        const int2* epk = epack + (size_t)rel * EB;
        const int base = soff[h][0];
        const int glo = soff[h][g] - base;
        const int ghi0 = soff[h][g + 1] - base;
        const int ghi = ghi0 < CAP ? ghi0 : CAP;   // LDS-resident part
        const int2* eb = ebuf[h];
        float acc[8] = {0.f, 0.f, 0.f, 0.f, 0.f, 0.f, 0.f, 0.f};

        if (glo < ghi) {
            uint4 rA0, rA1, rA2, rA3, rB0, rB1, rB2, rB3;
            float cA0, cA1, cA2, cA3, cB0, cB1, cB2, cB3;
            PREF(glo, cA0, cA1, cA2, cA3, rA0, rA1, rA2, rA3);
            for (int i = glo; i < ghi; i += 8) {
                bool hasB = (i + 4 < ghi);
                if (hasB) PREF(i + 4, cB0, cB1, cB2, cB3, rB0, rB1, rB2, rB3);
                FMA8(cA0, rA0); FMA8(cA1, rA1); FMA8(cA2, rA2); FMA8(cA3, rA3);
                if (i + 8 < ghi) PREF(i + 8, cA0, cA1, cA2, cA3, rA0, rA1, rA2, rA3);
                if (hasB) { FMA8(cB0, rB0); FMA8(cB1, rB1); FMA8(cB2, rB2); FMA8(cB3, rB3); }
            }
        }
        // rare overflow tail straight from global
        for (int i = (glo > CAP ? glo : CAP); i < ghi0; ++i) {
            int2 p = epk[base + i];
            float cc = __int_as_float(p.y);
            uint4 rr = *reinterpret_cast<const uint4*>(x + ((unsigned)p.x * D + cbase));
            FMA8(cc, rr);
        }
        int dg = ghi0 - glo;
        float di = rsqrtf((float)(dg > 1 ? dg : 1));
#pragma unroll
        for (int k = 0; k < 8; ++k) acc[k] *= di;
        *reinterpret_cast<float4*>(&S[g][h * 128 + cbase]) =
            make_float4(acc[0], acc[1], acc[2], acc[3]);
        *reinterpret_cast<float4*>(&S[g][h * 128 + cbase + 4]) =
            make_float4(acc[4], acc[5], acc[6], acc[7]);
    }
    __syncthreads();

    // ---- stage 2: GEMM [16,256] @ [256,128] ----
    const int rA = t, rB = 2 + t;
    const int j0 = (tid & 31) * 4, r0i = (tid >> 5) * 2;
    const float* WA = W + rA * D * D;
    const float* WB = W + rB * D * D;
    float acc2[2][4] = {{0.f, 0.f, 0.f, 0.f}, {0.f, 0.f, 0.f, 0.f}};
#pragma unroll 2
    for (int k0 = 0; k0 < 128; k0 += 4) {
        float4 s0 = *reinterpret_cast<const float4*>(&S[r0i][k0]);
        float4 s1 = *reinterpret_cast<const float4*>(&S[r0i + 1][k0]);
#pragma unroll
        for (int kk = 0; kk < 4; ++kk) {
            float4 w = *reinterpret_cast<const float4*>(WA + (k0 + kk) * D + j0);
            float e0 = (&s0.x)[kk], e1 = (&s1.x)[kk];
            acc2[0][0] = fmaf(e0, w.x, acc2[0][0]);
            acc2[0][1] = fmaf(e0, w.y, acc2[0][1]);
            acc2[0][2] = fmaf(e0, w.z, acc2[0][2]);
            acc2[0][3] = fmaf(e0, w.w, acc2[0][3]);
            acc2[1][0] = fmaf(e1, w.x, acc2[1][0]);
            acc2[1][1] = fmaf(e1, w.y, acc2[1][1]);
            acc2[1][2] = fmaf(e1, w.z, acc2[1][2]);
            acc2[1][3] = fmaf(e1, w.w, acc2[1][3]);
        }
    }
#pragma unroll 2
    for (int k0 = 0; k0 < 128; k0 += 4) {
        float4 s0 = *reinterpret_cast<const float4*>(&S[r0i][128 + k0]);
        float4 s1 = *reinterpret_cast<const float4*>(&S[r0i + 1][128 + k0]);
#pragma unroll
        for (int kk = 0; kk < 4; ++kk) {
            float4 w = *reinterpret_cast<const float4*>(WB + (k0 + kk) * D + j0);
            float e0 = (&s0.x)[kk], e1 = (&s1.x)[kk];
            acc2[0][0] = fmaf(e0, w.x, acc2[0][0]);
            acc2[0][1] = fmaf(e0, w.y, acc2[0][1]);
            acc2[0][2] = fmaf(e0, w.z, acc2[0][2]);
            acc2[0][3] = fmaf(e0, w.w, acc2[0][3]);
            acc2[1][0] = fmaf(e1, w.x, acc2[1][0]);
            acc2[1][1] = fmaf(e1, w.y, acc2[1][1]);
            acc2[1][2] = fmaf(e1, w.z, acc2[1][2]);
            acc2[1][3] = fmaf(e1, w.w, acc2[1][3]);
        }
    }

    // ---- epilogue: bias + PReLU + store ----
    float pa = prelu_a[0];
    const float* bA = b + rA * D;
    const float* bB = b + rB * D;
    float4 bb;
    bb.x = bA[j0 + 0] + bB[j0 + 0];
    bb.y = bA[j0 + 1] + bB[j0 + 1];
    bb.z = bA[j0 + 2] + bB[j0 + 2];
    bb.w = bA[j0 + 3] + bB[j0 + 3];
    float* o = out + (size_t)t * NB * D;
#pragma unroll
    for (int i = 0; i < 2; ++i) {
        float4 v;
        v.x = acc2[i][0] + bb.x;
        v.y = acc2[i][1] + bb.y;
        v.z = acc2[i][2] + bb.z;
        v.w = acc2[i][3] + bb.w;
        v.x = v.x >= 0.f ? v.x : pa * v.x;
        v.y = v.y >= 0.f ? v.y : pa * v.y;
        v.z = v.z >= 0.f ? v.z : pa * v.z;
        v.w = v.w >= 0.f ? v.w : pa * v.w;
        *reinterpret_cast<float4*>(o + (size_t)(row0 + r0i + i) * D + j0) = v;
    }
}

extern "C" void kernel_launch(void* const* d_in, const int* in_sizes, int n_in,
                              void* d_out, int out_size, void* d_ws, size_t ws_size,
                              hipStream_t stream) {
    const float* x_drug = (const float*)d_in[0];
    const float* x_dis  = (const float*)d_in[1];
    const float* W      = (const float*)d_in[2];   // [4,128,128]
    const float* b      = (const float*)d_in[3];   // [4,128]
    const float* pa     = (const float*)d_in[4];   // [1]
    EdgePtrs ep;
    ep.src[0] = (const int*)d_in[5];  ep.dst[0] = (const int*)d_in[6];   // dd
    ep.src[1] = (const int*)d_in[7];  ep.dst[1] = (const int*)d_in[8];   // ds
    ep.src[2] = (const int*)d_in[9];  ep.dst[2] = (const int*)d_in[10];  // sd
    ep.src[3] = (const int*)d_in[11]; ep.dst[3] = (const int*)d_in[12];  // ss

    // workspace layout (bytes)
    char* ws = (char*)d_ws;
    int*  cntout   = (int*)(ws + 0);         // 4*NB ints
    int*  cntin    = (int*)(ws + 800000);    // 4*NB ints
    int*  offs     = (int*)(ws + 1600000);   // 4*(NB+1) ints
    int*  chunksum = (int*)(ws + 2400064);   // 4*NCH ints
    int*  rank     = (int*)(ws + 2401664);   // 4*EB ints (8 MB)
    int2* epack    = (int2*)(ws + 10401664); // 4*EB int2 (16 MB)
    unsigned short* xb = (unsigned short*)(ws + 26401664); // 2*NB*D bf16 (25.6 MB)
    // total ~52 MB

    hipMemsetAsync(ws, 0, 1600000, stream);  // cntout, cntin

    k_deg_cvt<<<dim3(DEGBLK + CVTBLK, 4), 256, 0, stream>>>(
        ep, cntout, cntin, rank, x_drug, x_dis, xb);
    k_scan1<<<dim3(NCH, 4), 512, 0, stream>>>(cntin, offs, chunksum);
    k_scan2<<<1, 256, 0, stream>>>(chunksum);
    k_scan3<<<dim3(NCH, 4), 512, 0, stream>>>(offs, chunksum);
    k_fill<<<dim3(DEGBLK, 4), 256, 0, stream>>>(ep, cntout, offs, rank, epack);
    k_fused<<<dim3(NB / 16, 2), 256, 0, stream>>>(
        xb, W, b, pa, offs, epack, (float*)d_out);
}